// Round 5
// baseline (1097.086 us; speedup 1.0000x reference)
//
#include <hip/hip_runtime.h>
#include <math.h>

// Problem constants (B=4, S=2048, D=1024, H=16, d_k=64)
#define B_  4
#define S_  2048
#define D_  1024
#define H_  16
#define DK_ 64

typedef unsigned short u16;
typedef unsigned int   u32;
typedef short     shortx8  __attribute__((ext_vector_type(8)));
typedef short     short4v  __attribute__((ext_vector_type(4)));
typedef float     floatx4  __attribute__((ext_vector_type(4)));
typedef float     floatx16 __attribute__((ext_vector_type(16)));
typedef u16       u16x4    __attribute__((ext_vector_type(4)));

// ---- bf16 helpers (RNE) ----
__device__ __forceinline__ u16 f2bf(float f) {
    u32 u = __float_as_uint(f);
    u += 0x7FFFu + ((u >> 16) & 1u);
    return (u16)(u >> 16);
}
__device__ __forceinline__ float bf2f(u16 b) {
    return __uint_as_float(((u32)b) << 16);
}

// ---- async global->LDS 16B (GEMM staging) ----
typedef const __attribute__((address_space(1))) u32* gp1_t;
typedef __attribute__((address_space(3))) u32* lp3_t;
__device__ __forceinline__ void async16(const void* g, void* l) {
    __builtin_amdgcn_global_load_lds((gp1_t)g, (lp3_t)l, 16, 0, 0);
}

#define MFMA32(a, b, c) __builtin_amdgcn_mfma_f32_16x16x32_bf16((a), (b), (c), 0, 0, 0)
#define MFMA16(a, b, c) __builtin_amdgcn_mfma_f32_32x32x16_bf16((a), (b), (c), 0, 0, 0)
// v_mfma_f32_32x32x8_bf16 (gfx950 ISA §10); clang builtin keeps the CDNA2 "_1k" name.
// NOTE: do NOT wrap in __has_builtin — host pass returns false for aux-target
// builtins and a fallback path breaks host compilation (round-4 lesson).
#define MFMA8(a, b, c)  __builtin_amdgcn_mfma_f32_32x32x8bf16_1k((a), (b), (c), 0, 0, 0)

// ---------------------------------------------------------------------------
// split fp32 -> (hi, lo) bf16 planes
// ---------------------------------------------------------------------------
__global__ __launch_bounds__(256)
void split_bf16(const float* __restrict__ src, u16* __restrict__ dh,
                u16* __restrict__ dl, int n)
{
    int i = (blockIdx.x * 256 + threadIdx.x) * 4;
    if (i >= n) return;
    float4 v = *(const float4*)(src + i);
    u16 h0 = f2bf(v.x), h1 = f2bf(v.y), h2 = f2bf(v.z), h3 = f2bf(v.w);
    u16x4 hv = {h0, h1, h2, h3};
    u16x4 lv = {f2bf(v.x - bf2f(h0)), f2bf(v.y - bf2f(h1)),
                f2bf(v.z - bf2f(h2)), f2bf(v.w - bf2f(h3))};
    *(u16x4*)(dh + i) = hv;
    *(u16x4*)(dl + i) = lv;
}

// ---------------------------------------------------------------------------
// bf16x3 GEMM: C[M][N] = (Ah+Al)[M][K] @ (Wh+Wl)[N][K]^T  (3 MFMA passes)
// 128x128 tile, BK=32, 256 threads = 4 waves (2x2), 64x64 per wave.
// 1-D grid, XCD-swizzled (nwg % 8 == 0). Output plane stride is D_.
// EPI 0: fp32 out.  EPI 3: fused QKV epilogue (sel by n0>>10):
//        sel0 Q: RoPE + 1/8 -> qoh/qol; sel1 K: RoPE -> koh/kol; sel2 V -> voh.
// ---------------------------------------------------------------------------
template<int EPI>
__global__ __launch_bounds__(256)
void gemm_b3(const u16* __restrict__ Ah, const u16* __restrict__ Al,
             const u16* __restrict__ Wh, const u16* __restrict__ Wl,
             float* __restrict__ outF,
             u16* __restrict__ qoh, u16* __restrict__ qol,
             u16* __restrict__ koh, u16* __restrict__ kol,
             u16* __restrict__ voh,
             int M, int N, int K, int mtiles)
{
    __shared__ __align__(16) u16 As[2][128][32];
    __shared__ __align__(16) u16 Ws[2][128][32];

    const int tid  = threadIdx.x;
    const int w    = tid >> 6;
    const int lane = tid & 63;
    const int lr   = lane & 15, lg = lane >> 4;
    const int wm   = w >> 1, wn = w & 1;

    // XCD-aware bijective swizzle (nwg multiple of 8)
    const int cpx = gridDim.x >> 3;
    const int id  = blockIdx.x;
    const int swz = (id & 7) * cpx + (id >> 3);
    const int mt  = swz % mtiles, nt = swz / mtiles;
    const int m0  = mt * 128, n0 = nt * 128;

    const int srow = w * 32 + (lane >> 2);
    const int sck  = (lane & 3) * 8;
    const u16* gAh = Ah + (size_t)(m0 + srow) * K + sck;
    const u16* gAl = Al + (size_t)(m0 + srow) * K + sck;
    const u16* gWh = Wh + (size_t)(n0 + srow) * K + sck;
    const u16* gWl = Wl + (size_t)(n0 + srow) * K + sck;
    const size_t r16 = (size_t)16 * K;

    u16* dAh = &As[0][w * 32][0];
    u16* dAl = &As[1][w * 32][0];
    u16* dWh = &Ws[0][w * 32][0];
    u16* dWl = &Ws[1][w * 32][0];

    floatx4 zero = {0.f, 0.f, 0.f, 0.f};
    floatx4 acc[4][4];
    #pragma unroll
    for (int i = 0; i < 4; ++i)
        #pragma unroll
        for (int j = 0; j < 4; ++j) acc[i][j] = zero;

    for (int kt = 0; kt < K; kt += 32) {
        __syncthreads();
        async16(gAh + kt,       dAh);
        async16(gAh + kt + r16, dAh + 512);
        async16(gAl + kt,       dAl);
        async16(gAl + kt + r16, dAl + 512);
        async16(gWh + kt,       dWh);
        async16(gWh + kt + r16, dWh + 512);
        async16(gWl + kt,       dWl);
        async16(gWl + kt + r16, dWl + 512);
        __syncthreads();

        shortx8 a[4][2], bw[4][2];
        #pragma unroll
        for (int mi = 0; mi < 4; ++mi) {
            a[mi][0] = *(const shortx8*)&As[0][wm * 64 + mi * 16 + lr][lg * 8];
            a[mi][1] = *(const shortx8*)&As[1][wm * 64 + mi * 16 + lr][lg * 8];
        }
        #pragma unroll
        for (int ni = 0; ni < 4; ++ni) {
            bw[ni][0] = *(const shortx8*)&Ws[0][wn * 64 + ni * 16 + lr][lg * 8];
            bw[ni][1] = *(const shortx8*)&Ws[1][wn * 64 + ni * 16 + lr][lg * 8];
        }
        #pragma unroll
        for (int mi = 0; mi < 4; ++mi)
            #pragma unroll
            for (int ni = 0; ni < 4; ++ni) {
                acc[mi][ni] = MFMA32(a[mi][0], bw[ni][0], acc[mi][ni]);
                acc[mi][ni] = MFMA32(a[mi][0], bw[ni][1], acc[mi][ni]);
                acc[mi][ni] = MFMA32(a[mi][1], bw[ni][0], acc[mi][ni]);
            }
    }

    // C value (mi,ni,r): row = m0+wm*64+mi*16+lg*4+r, col = n0+wn*64+ni*16+lr
    if constexpr (EPI == 0) {
        #pragma unroll
        for (int mi = 0; mi < 4; ++mi)
            #pragma unroll
            for (int ni = 0; ni < 4; ++ni)
                #pragma unroll
                for (int r = 0; r < 4; ++r) {
                    size_t row = m0 + wm * 64 + mi * 16 + lg * 4 + r;
                    size_t col = n0 + wn * 64 + ni * 16 + lr;
                    outF[row * D_ + col] = acc[mi][ni][r];
                }
    }
    if constexpr (EPI == 3) {
        const int sel = n0 >> 10;
        const int ln0 = n0 & 1023;
        if (sel <= 1) {                         // Q or K: RoPE + hi/lo planes
            const float scale = (sel == 0) ? 0.125f : 1.0f;
            u16* oh = (sel == 0) ? qoh : koh;
            u16* ol = (sel == 0) ? qol : kol;
            #pragma unroll
            for (int ni = 0; ni < 4; ++ni) {
                int din  = ni * 16 + lr;        // d within head
                float fr = powf(10000.0f, -(float)(din >> 1) * (1.0f / 32.0f));
                #pragma unroll
                for (int mi = 0; mi < 4; ++mi)
                    #pragma unroll
                    for (int r = 0; r < 4; ++r) {
                        int row  = m0 + wm * 64 + mi * 16 + lg * 4 + r;
                        float v  = acc[mi][ni][r];
                        float pv = __shfl_xor(v, 1);
                        float sa, ca;
                        sincosf((float)(row & (S_ - 1)) * fr, &sa, &ca);
                        float o = (v * ca + ((lr & 1) ? pv * sa : -pv * sa)) * scale;
                        u16 hv = f2bf(o);
                        u16 lv = f2bf(o - bf2f(hv));
                        u32 ph  = (u32)__shfl_xor((int)hv, 1) & 0xFFFFu;
                        u32 pl2 = (u32)__shfl_xor((int)lv, 1) & 0xFFFFu;
                        if (!(lr & 1)) {
                            size_t off = (size_t)row * D_ + ln0 + wn * 64 + ni * 16 + lr;
                            *(u32*)(oh + off) = (u32)hv | (ph << 16);
                            *(u32*)(ol + off) = (u32)lv | (pl2 << 16);
                        }
                    }
            }
        } else {                                // V: bf16-hi only
            #pragma unroll
            for (int mi = 0; mi < 4; ++mi)
                #pragma unroll
                for (int ni = 0; ni < 4; ++ni)
                    #pragma unroll
                    for (int r = 0; r < 4; ++r) {
                        float v = acc[mi][ni][r];
                        u16 hv = f2bf(v);
                        u32 ph = (u32)__shfl_xor((int)hv, 1) & 0xFFFFu;
                        if (!(lr & 1)) {
                            size_t row = m0 + wm * 64 + mi * 16 + lg * 4 + r;
                            size_t off = row * D_ + ln0 + wn * 64 + ni * 16 + lr;
                            *(u32*)(voh + off) = (u32)hv | (ph << 16);
                        }
                    }
        }
    }
}

// ---------------------------------------------------------------------------
// Flash attention v2 — swapped-operand MFMA, in-register softmax.
// Block = (qt: 128 q-rows, h, b), 4 waves, wave = 32 q-rows (q = lane&31).
// S^T = mfma(A=K, B=Q) with 32x32x16 (gfx950-native, half the instructions):
//   lane holds 32 scores for ITS q-row -> softmax local tree + ONE shfl_xor(32).
// PV uses 32x32x8: B-frag k-map ((l>>5)*4+j) == C-reg key-map -> P feeds PV
//   from REGISTERS (no P LDS tile, no extra barriers, no conflicts).
// K (hi/lo) row-major LDS [64][72] (144B rows: b128-aligned, 4-way banks);
// V^T [64][68] (8B reads, 2-way = free). QK^T bf16x3; PV bf16.
// O written as hi/lo planes (aliases Q: block-disjoint regions).
// ---------------------------------------------------------------------------
__global__ __launch_bounds__(256)
void attn_mfma(const u16* __restrict__ Qh, const u16* __restrict__ Ql,
               const u16* __restrict__ Kh, const u16* __restrict__ Kl,
               const u16* __restrict__ Vh,
               u16* __restrict__ Oh, u16* __restrict__ Ol)
{
    __shared__ __align__(16) u16 Ksh[64][72];
    __shared__ __align__(16) u16 Ksl[64][72];
    __shared__ __align__(16) u16 Vt[64][68];

    const int tid  = threadIdx.x, w = tid >> 6, lane = tid & 63;
    const int l31  = lane & 31, hi = lane >> 5;
    const int qt   = gridDim.x - 1 - blockIdx.x;   // heavy tiles dispatch first
    const int h    = blockIdx.y, b = blockIdx.z;
    const int q0   = qt * 128;
    const size_t rowbase = (size_t)b * S_;
    const int qg   = q0 + w * 32 + l31;            // this lane's q row

    // Q fragments (B-operand, 32x32x16): chunk c covers k = c*16 + hi*8 + j
    shortx8 qfh[4], qfl[4];
    {
        const u16* qp  = Qh + (rowbase + qg) * D_ + h * DK_ + hi * 8;
        const u16* qp2 = Ql + (rowbase + qg) * D_ + h * DK_ + hi * 8;
        #pragma unroll
        for (int c = 0; c < 4; ++c) {
            qfh[c] = *(const shortx8*)(qp  + c * 16);
            qfl[c] = *(const shortx8*)(qp2 + c * 16);
        }
    }

    // staging addresses (tile 0)
    const int kr = tid >> 2, kc = (tid & 3) * 16;
    const u16* gKh = Kh + (rowbase + kr) * D_ + h * DK_ + kc;
    const u16* gKl = Kl + (rowbase + kr) * D_ + h * DK_ + kc;
    const u16* gV  = Vh + (rowbase + lane) * D_ + h * DK_ + w * 16;

    shortx8 rkh[2], rkl[2], rv[2];
    rkh[0] = *(const shortx8*)(gKh);   rkh[1] = *(const shortx8*)(gKh + 8);
    rkl[0] = *(const shortx8*)(gKl);   rkl[1] = *(const shortx8*)(gKl + 8);
    rv[0]  = *(const shortx8*)(gV);    rv[1]  = *(const shortx8*)(gV + 8);

    float mrow = -1e30f, lsum = 0.0f;
    floatx16 oacc[2] = {};

    const int nkt = 2 * qt + 2;
    for (int kt = 0; kt < nkt; ++kt) {
        __syncthreads();                       // prev tile's LDS reads done
        *(shortx8*)&Ksh[kr][kc]     = rkh[0];
        *(shortx8*)&Ksh[kr][kc + 8] = rkh[1];
        *(shortx8*)&Ksl[kr][kc]     = rkl[0];
        *(shortx8*)&Ksl[kr][kc + 8] = rkl[1];
        #pragma unroll
        for (int j = 0; j < 8; ++j) {          // V transpose: Vt[d][key]
            Vt[w * 16 + j][lane]     = (u16)rv[0][j];
            Vt[w * 16 + 8 + j][lane] = (u16)rv[1][j];
        }
        __syncthreads();

        if (kt < nkt - 1) {                    // prefetch next tile into regs
            gKh += (size_t)64 * D_; gKl += (size_t)64 * D_; gV += (size_t)64 * D_;
            rkh[0] = *(const shortx8*)(gKh);   rkh[1] = *(const shortx8*)(gKh + 8);
            rkl[0] = *(const shortx8*)(gKl);   rkl[1] = *(const shortx8*)(gKl + 8);
            rv[0]  = *(const shortx8*)(gV);    rv[1]  = *(const shortx8*)(gV + 8);
        }

        // ---- S^T = K @ Q^T (bf16x3, 32x32x16): sc[kf] = keys kf*32.. ----
        floatx16 sc[2] = {};
        __builtin_amdgcn_s_setprio(1);
        #pragma unroll
        for (int kf = 0; kf < 2; ++kf)
            #pragma unroll
            for (int c = 0; c < 4; ++c) {
                shortx8 ah = *(const shortx8*)&Ksh[kf * 32 + l31][c * 16 + hi * 8];
                shortx8 al = *(const shortx8*)&Ksl[kf * 32 + l31][c * 16 + hi * 8];
                sc[kf] = MFMA16(ah, qfh[c], sc[kf]);
                sc[kf] = MFMA16(al, qfh[c], sc[kf]);
                sc[kf] = MFMA16(ah, qfl[c], sc[kf]);
            }
        __builtin_amdgcn_s_setprio(0);

        // ---- causal mask (only tiles overlapping the diagonal zone) ----
        const int k0 = kt * 64;
        if (kt >= 2 * qt) {
            #pragma unroll
            for (int kf = 0; kf < 2; ++kf)
                #pragma unroll
                for (int r = 0; r < 16; ++r) {
                    int key = k0 + kf * 32 + (r & 3) + 8 * (r >> 2) + 4 * hi;
                    if (key > qg) sc[kf][r] = -1e30f;
                }
        }

        // ---- online softmax: row is lane-local + one xor(32) ----
        float t0 = -1e30f, t1 = -1e30f, t2 = -1e30f, t3 = -1e30f;
        #pragma unroll
        for (int kf = 0; kf < 2; ++kf)
            #pragma unroll
            for (int r = 0; r < 16; r += 4) {
                t0 = fmaxf(t0, sc[kf][r + 0]);
                t1 = fmaxf(t1, sc[kf][r + 1]);
                t2 = fmaxf(t2, sc[kf][r + 2]);
                t3 = fmaxf(t3, sc[kf][r + 3]);
            }
        float pm = fmaxf(fmaxf(t0, t1), fmaxf(t2, t3));
        pm = fmaxf(pm, __shfl_xor(pm, 32));
        const float mn   = fmaxf(mrow, pm);
        const float corr = __expf(mrow - mn);
        mrow = mn;
        float s0 = 0.f, s1 = 0.f, s2 = 0.f, s3 = 0.f;
        #pragma unroll
        for (int kf = 0; kf < 2; ++kf)
            #pragma unroll
            for (int r = 0; r < 16; r += 4) {
                s0 += (sc[kf][r + 0] = __expf(sc[kf][r + 0] - mn));
                s1 += (sc[kf][r + 1] = __expf(sc[kf][r + 1] - mn));
                s2 += (sc[kf][r + 2] = __expf(sc[kf][r + 2] - mn));
                s3 += (sc[kf][r + 3] = __expf(sc[kf][r + 3] - mn));
            }
        float ls = (s0 + s1) + (s2 + s3);
        ls += __shfl_xor(ls, 32);
        lsum = lsum * corr + ls;
        oacc[0] *= corr;
        oacc[1] *= corr;

        // ---- pack P -> bf16 B-frags (pure register, no LDS) ----
        // pb[kc2][j] = P^T[key = kc2*8 + hi*4 + j][q = l31]
        short4v pb[8];
        #pragma unroll
        for (int kc2 = 0; kc2 < 8; ++kc2)
            #pragma unroll
            for (int j = 0; j < 4; ++j)
                pb[kc2][j] = (short)f2bf(sc[kc2 >> 2][(kc2 & 3) * 4 + j]);

        // ---- O^T += V^T @ P^T (32x32x8) ----
        __builtin_amdgcn_s_setprio(1);
        #pragma unroll
        for (int kc2 = 0; kc2 < 8; ++kc2) {
            short4v va0 = *(const short4v*)&Vt[l31][kc2 * 8 + hi * 4];
            short4v va1 = *(const short4v*)&Vt[32 + l31][kc2 * 8 + hi * 4];
            oacc[0] = MFMA8(va0, pb[kc2], oacc[0]);
            oacc[1] = MFMA8(va1, pb[kc2], oacc[1]);
        }
        __builtin_amdgcn_s_setprio(0);
    }

    // ---- epilogue: O^T regs -> O[q][d] hi/lo planes (u32 d-pair stores) ----
    const float inv = 1.0f / lsum;
    #pragma unroll
    for (int df = 0; df < 2; ++df)
        #pragma unroll
        for (int rp = 0; rp < 8; ++rp) {
            const int r0 = rp * 2;
            const int d  = df * 32 + (r0 & 3) + 8 * (r0 >> 2) + 4 * hi;
            float v0 = oacc[df][r0] * inv;
            float v1 = oacc[df][r0 + 1] * inv;
            u16 h0 = f2bf(v0), h1 = f2bf(v1);
            u16 e0 = f2bf(v0 - bf2f(h0)), e1 = f2bf(v1 - bf2f(h1));
            size_t off = (rowbase + qg) * D_ + h * DK_ + d;
            *(u32*)(Oh + off) = (u32)h0 | ((u32)h1 << 16);
            *(u32*)(Ol + off) = (u32)e0 | ((u32)e1 << 16);
        }
}

// ---------------------------------------------------------------------------
// Launch
// ---------------------------------------------------------------------------
extern "C" void kernel_launch(void* const* d_in, const int* in_sizes, int n_in,
                              void* d_out, int out_size, void* d_ws, size_t ws_size,
                              hipStream_t stream)
{
    const float* x   = (const float*)d_in[0];
    const float* w_q = (const float*)d_in[1];
    const float* w_k = (const float*)d_in[2];
    const float* w_v = (const float*)d_in[3];
    const float* w_o = (const float*)d_in[4];
    float* out = (float*)d_out;

    const size_t TEN = (size_t)B_ * S_ * D_;   // 8388608
    const int    DD  = D_ * D_;                // 1048576
    const int    M   = B_ * S_;                // 8192

    u16* p    = (u16*)d_ws;
    u16* xh   = p;             u16* xl   = xh + TEN;
    u16* qh   = xl + TEN;      u16* ql   = qh + TEN;   // reused as attn out hi/lo
    u16* kh   = ql + TEN;      u16* kl   = kh + TEN;
    u16* vh   = kl + TEN;
    u16* wch  = vh + TEN;                              // concat QKV weights hi [3072][1024]
    u16* wcl  = wch + (size_t)3 * DD;                  // concat QKV weights lo
    u16* woh  = wcl + (size_t)3 * DD;
    u16* wol  = woh + DD;

    // 1) split fp32 -> bf16 hi/lo planes (QKV weights into concat buffer)
    split_bf16<<<(int)(TEN / 1024), 256, 0, stream>>>(x, xh, xl, (int)TEN);
    split_bf16<<<DD / 1024, 256, 0, stream>>>(w_q, wch,          wcl,          DD);
    split_bf16<<<DD / 1024, 256, 0, stream>>>(w_k, wch + DD,     wcl + DD,     DD);
    split_bf16<<<DD / 1024, 256, 0, stream>>>(w_v, wch + 2 * DD, wcl + 2 * DD, DD);
    split_bf16<<<DD / 1024, 256, 0, stream>>>(w_o, woh, wol, DD);

    // 2) fused QKV projection (RoPE in epilogue; Q pre-scaled by 1/8)
    gemm_b3<3><<<dim3((M / 128) * (3 * D_ / 128)), 256, 0, stream>>>(
        xh, xl, wch, wcl, nullptr, qh, ql, kh, kl, vh, M, 3 * D_, D_, M / 128);

    // 3) flash attention v2 (output aliases q planes; block-disjoint regions)
    attn_mfma<<<dim3(S_ / 128, H_, B_), 256, 0, stream>>>(qh, ql, kh, kl, vh,
                                                          qh, ql);

    // 4) output projection -> fp32
    gemm_b3<0><<<dim3((M / 128) * (D_ / 128)), 256, 0, stream>>>(
        qh, ql, woh, wol, out, nullptr, nullptr, nullptr, nullptr, nullptr,
        M, D_, D_, M / 128);
}

// Round 6
// 544.182 us; speedup vs baseline: 2.0160x; 2.0160x over previous
//
#include <hip/hip_runtime.h>
#include <math.h>

// Problem constants (B=4, S=2048, D=1024, H=16, d_k=64)
#define B_  4
#define S_  2048
#define D_  1024
#define H_  16
#define DK_ 64

typedef unsigned short u16;
typedef unsigned int   u32;
typedef short     shortx8  __attribute__((ext_vector_type(8)));
typedef short     short4v  __attribute__((ext_vector_type(4)));
typedef float     floatx4  __attribute__((ext_vector_type(4)));
typedef float     floatx16 __attribute__((ext_vector_type(16)));
typedef u16       u16x4    __attribute__((ext_vector_type(4)));

// ---- bf16 helpers (RNE) ----
__device__ __forceinline__ u16 f2bf(float f) {
    u32 u = __float_as_uint(f);
    u += 0x7FFFu + ((u >> 16) & 1u);
    return (u16)(u >> 16);
}
__device__ __forceinline__ float bf2f(u16 b) {
    return __uint_as_float(((u32)b) << 16);
}

// ---- async global->LDS 16B (GEMM staging) ----
typedef const __attribute__((address_space(1))) u32* gp1_t;
typedef __attribute__((address_space(3))) u32* lp3_t;
__device__ __forceinline__ void async16(const void* g, void* l) {
    __builtin_amdgcn_global_load_lds((gp1_t)g, (lp3_t)l, 16, 0, 0);
}

#define MFMA32(a, b, c) __builtin_amdgcn_mfma_f32_16x16x32_bf16((a), (b), (c), 0, 0, 0)
#define MFMA16(a, b, c) __builtin_amdgcn_mfma_f32_32x32x16_bf16((a), (b), (c), 0, 0, 0)
// v_mfma_f32_32x32x8_bf16 (gfx950 ISA §10); clang builtin keeps the CDNA2 "_1k" name.
#define MFMA8(a, b, c)  __builtin_amdgcn_mfma_f32_32x32x8bf16_1k((a), (b), (c), 0, 0, 0)

// ---------------------------------------------------------------------------
// split fp32 -> (hi, lo) bf16 planes
// ---------------------------------------------------------------------------
__global__ __launch_bounds__(256)
void split_bf16(const float* __restrict__ src, u16* __restrict__ dh,
                u16* __restrict__ dl, int n)
{
    int i = (blockIdx.x * 256 + threadIdx.x) * 4;
    if (i >= n) return;
    float4 v = *(const float4*)(src + i);
    u16 h0 = f2bf(v.x), h1 = f2bf(v.y), h2 = f2bf(v.z), h3 = f2bf(v.w);
    u16x4 hv = {h0, h1, h2, h3};
    u16x4 lv = {f2bf(v.x - bf2f(h0)), f2bf(v.y - bf2f(h1)),
                f2bf(v.z - bf2f(h2)), f2bf(v.w - bf2f(h3))};
    *(u16x4*)(dh + i) = hv;
    *(u16x4*)(dl + i) = lv;
}

// ---------------------------------------------------------------------------
// RoPE cos/sin table: tab[s*32 + i] = (cos(s*f_i), sin(s*f_i)),
// f_i = 10000^(-i/32).  65536 entries = 512 KB, L2-hot thereafter.
// ---------------------------------------------------------------------------
__global__ __launch_bounds__(256)
void fill_rope(float2* __restrict__ tab)
{
    const int idx = blockIdx.x * 256 + threadIdx.x;   // 65536 total
    const int s = idx >> 5, i = idx & 31;
    const float fr = powf(10000.0f, -(float)i * (1.0f / 32.0f));
    float sa, ca;
    sincosf((float)s * fr, &sa, &ca);
    tab[idx] = make_float2(ca, sa);
}

// ---------------------------------------------------------------------------
// bf16x3 GEMM: C[M][N] = (Ah+Al)[M][K] @ (Wh+Wl)[N][K]^T  (3 MFMA passes)
// 128x128 tile, BK=32, 256 threads = 4 waves (2x2), 64x64 per wave.
// 1-D grid, XCD-swizzled; mtiles hard-coded 64 (M=8192 always).
// __launch_bounds__(256,1): full VGPR budget — round-5 showed the default
// target spilled acc (VGPR=76, 3.2 GB scratch writes, 780 us).
// A-fragments loaded per-mi inside the MFMA loop to cut live registers.
// EPI 0: fp32 out.  EPI 3: fused QKV epilogue (sel by n0>>10), RoPE via table.
// ---------------------------------------------------------------------------
template<int EPI>
__global__ __launch_bounds__(256, 1)
void gemm_b3(const u16* __restrict__ Ah, const u16* __restrict__ Al,
             const u16* __restrict__ Wh, const u16* __restrict__ Wl,
             float* __restrict__ outF,
             u16* __restrict__ qoh, u16* __restrict__ qol,
             u16* __restrict__ koh, u16* __restrict__ kol,
             u16* __restrict__ voh,
             const float2* __restrict__ rope,
             int M, int N, int K)
{
    __shared__ __align__(16) u16 As[2][128][32];
    __shared__ __align__(16) u16 Ws[2][128][32];

    const int tid  = threadIdx.x;
    const int w    = tid >> 6;
    const int lane = tid & 63;
    const int lr   = lane & 15, lg = lane >> 4;
    const int wm   = w >> 1, wn = w & 1;

    // XCD-aware bijective swizzle (nwg multiple of 8); mtiles = 64
    const int cpx = gridDim.x >> 3;
    const int id  = blockIdx.x;
    const int swz = (id & 7) * cpx + (id >> 3);
    const int m0  = (swz & 63) * 128, n0 = (swz >> 6) * 128;

    const int srow = w * 32 + (lane >> 2);
    const int sck  = (lane & 3) * 8;
    const u16* gAh = Ah + (size_t)(m0 + srow) * K + sck;
    const u16* gAl = Al + (size_t)(m0 + srow) * K + sck;
    const u16* gWh = Wh + (size_t)(n0 + srow) * K + sck;
    const u16* gWl = Wl + (size_t)(n0 + srow) * K + sck;
    const size_t r16 = (size_t)16 * K;

    u16* dAh = &As[0][w * 32][0];
    u16* dAl = &As[1][w * 32][0];
    u16* dWh = &Ws[0][w * 32][0];
    u16* dWl = &Ws[1][w * 32][0];

    floatx4 zero = {0.f, 0.f, 0.f, 0.f};
    floatx4 acc[4][4];
    #pragma unroll
    for (int i = 0; i < 4; ++i)
        #pragma unroll
        for (int j = 0; j < 4; ++j) acc[i][j] = zero;

    for (int kt = 0; kt < K; kt += 32) {
        __syncthreads();
        async16(gAh + kt,       dAh);
        async16(gAh + kt + r16, dAh + 512);
        async16(gAl + kt,       dAl);
        async16(gAl + kt + r16, dAl + 512);
        async16(gWh + kt,       dWh);
        async16(gWh + kt + r16, dWh + 512);
        async16(gWl + kt,       dWl);
        async16(gWl + kt + r16, dWl + 512);
        __syncthreads();

        // B-fragments resident (32 VGPR); A-fragments streamed per-mi.
        shortx8 bw0[4], bw1[4];
        #pragma unroll
        for (int ni = 0; ni < 4; ++ni) {
            bw0[ni] = *(const shortx8*)&Ws[0][wn * 64 + ni * 16 + lr][lg * 8];
            bw1[ni] = *(const shortx8*)&Ws[1][wn * 64 + ni * 16 + lr][lg * 8];
        }
        #pragma unroll
        for (int mi = 0; mi < 4; ++mi) {
            shortx8 a0 = *(const shortx8*)&As[0][wm * 64 + mi * 16 + lr][lg * 8];
            shortx8 a1 = *(const shortx8*)&As[1][wm * 64 + mi * 16 + lr][lg * 8];
            #pragma unroll
            for (int ni = 0; ni < 4; ++ni) {
                acc[mi][ni] = MFMA32(a0, bw0[ni], acc[mi][ni]);
                acc[mi][ni] = MFMA32(a0, bw1[ni], acc[mi][ni]);
                acc[mi][ni] = MFMA32(a1, bw0[ni], acc[mi][ni]);
            }
        }
    }

    // C value (mi,ni,r): row = m0+wm*64+mi*16+lg*4+r, col = n0+wn*64+ni*16+lr
    if constexpr (EPI == 0) {
        #pragma unroll
        for (int mi = 0; mi < 4; ++mi)
            #pragma unroll
            for (int ni = 0; ni < 4; ++ni)
                #pragma unroll
                for (int r = 0; r < 4; ++r) {
                    size_t row = m0 + wm * 64 + mi * 16 + lg * 4 + r;
                    size_t col = n0 + wn * 64 + ni * 16 + lr;
                    outF[row * D_ + col] = acc[mi][ni][r];
                }
    }
    if constexpr (EPI == 3) {
        const int sel = n0 >> 10;
        const int ln0 = n0 & 1023;
        if (sel <= 1) {                         // Q or K: RoPE + hi/lo planes
            const float scale = (sel == 0) ? 0.125f : 1.0f;
            u16* oh = (sel == 0) ? qoh : koh;
            u16* ol = (sel == 0) ? qol : kol;
            #pragma unroll
            for (int ni = 0; ni < 4; ++ni) {
                const int pi = (ni * 16 + lr) >> 1;    // pair index 0..31
                #pragma unroll
                for (int mi = 0; mi < 4; ++mi)
                    #pragma unroll
                    for (int r = 0; r < 4; ++r) {
                        int row  = m0 + wm * 64 + mi * 16 + lg * 4 + r;
                        float2 cs = rope[((row & (S_ - 1)) << 5) + pi];
                        float v  = acc[mi][ni][r];
                        float pv = __shfl_xor(v, 1);
                        float o  = (v * cs.x + ((lr & 1) ? pv * cs.y : -pv * cs.y)) * scale;
                        u16 hv = f2bf(o);
                        u16 lv = f2bf(o - bf2f(hv));
                        u32 ph  = (u32)__shfl_xor((int)hv, 1) & 0xFFFFu;
                        u32 pl2 = (u32)__shfl_xor((int)lv, 1) & 0xFFFFu;
                        if (!(lr & 1)) {
                            size_t off = (size_t)row * D_ + ln0 + wn * 64 + ni * 16 + lr;
                            *(u32*)(oh + off) = (u32)hv | (ph << 16);
                            *(u32*)(ol + off) = (u32)lv | (pl2 << 16);
                        }
                    }
            }
        } else {                                // V: bf16-hi only
            #pragma unroll
            for (int mi = 0; mi < 4; ++mi)
                #pragma unroll
                for (int ni = 0; ni < 4; ++ni)
                    #pragma unroll
                    for (int r = 0; r < 4; ++r) {
                        float v = acc[mi][ni][r];
                        u16 hv = f2bf(v);
                        u32 ph = (u32)__shfl_xor((int)hv, 1) & 0xFFFFu;
                        if (!(lr & 1)) {
                            size_t row = m0 + wm * 64 + mi * 16 + lg * 4 + r;
                            size_t off = row * D_ + ln0 + wn * 64 + ni * 16 + lr;
                            *(u32*)(voh + off) = (u32)hv | (ph << 16);
                        }
                    }
        }
    }
}

// ---------------------------------------------------------------------------
// Flash attention v2 — swapped-operand MFMA, in-register softmax.
// (unchanged from round 5 — passed; left untouched for clean attribution)
// ---------------------------------------------------------------------------
__global__ __launch_bounds__(256)
void attn_mfma(const u16* __restrict__ Qh, const u16* __restrict__ Ql,
               const u16* __restrict__ Kh, const u16* __restrict__ Kl,
               const u16* __restrict__ Vh,
               u16* __restrict__ Oh, u16* __restrict__ Ol)
{
    __shared__ __align__(16) u16 Ksh[64][72];
    __shared__ __align__(16) u16 Ksl[64][72];
    __shared__ __align__(16) u16 Vt[64][68];

    const int tid  = threadIdx.x, w = tid >> 6, lane = tid & 63;
    const int l31  = lane & 31, hi = lane >> 5;
    const int qt   = gridDim.x - 1 - blockIdx.x;   // heavy tiles dispatch first
    const int h    = blockIdx.y, b = blockIdx.z;
    const int q0   = qt * 128;
    const size_t rowbase = (size_t)b * S_;
    const int qg   = q0 + w * 32 + l31;            // this lane's q row

    // Q fragments (B-operand, 32x32x16): chunk c covers k = c*16 + hi*8 + j
    shortx8 qfh[4], qfl[4];
    {
        const u16* qp  = Qh + (rowbase + qg) * D_ + h * DK_ + hi * 8;
        const u16* qp2 = Ql + (rowbase + qg) * D_ + h * DK_ + hi * 8;
        #pragma unroll
        for (int c = 0; c < 4; ++c) {
            qfh[c] = *(const shortx8*)(qp  + c * 16);
            qfl[c] = *(const shortx8*)(qp2 + c * 16);
        }
    }

    // staging addresses (tile 0)
    const int kr = tid >> 2, kc = (tid & 3) * 16;
    const u16* gKh = Kh + (rowbase + kr) * D_ + h * DK_ + kc;
    const u16* gKl = Kl + (rowbase + kr) * D_ + h * DK_ + kc;
    const u16* gV  = Vh + (rowbase + lane) * D_ + h * DK_ + w * 16;

    shortx8 rkh[2], rkl[2], rv[2];
    rkh[0] = *(const shortx8*)(gKh);   rkh[1] = *(const shortx8*)(gKh + 8);
    rkl[0] = *(const shortx8*)(gKl);   rkl[1] = *(const shortx8*)(gKl + 8);
    rv[0]  = *(const shortx8*)(gV);    rv[1]  = *(const shortx8*)(gV + 8);

    float mrow = -1e30f, lsum = 0.0f;
    floatx16 oacc[2] = {};

    const int nkt = 2 * qt + 2;
    for (int kt = 0; kt < nkt; ++kt) {
        __syncthreads();                       // prev tile's LDS reads done
        *(shortx8*)&Ksh[kr][kc]     = rkh[0];
        *(shortx8*)&Ksh[kr][kc + 8] = rkh[1];
        *(shortx8*)&Ksl[kr][kc]     = rkl[0];
        *(shortx8*)&Ksl[kr][kc + 8] = rkl[1];
        #pragma unroll
        for (int j = 0; j < 8; ++j) {          // V transpose: Vt[d][key]
            Vt[w * 16 + j][lane]     = (u16)rv[0][j];
            Vt[w * 16 + 8 + j][lane] = (u16)rv[1][j];
        }
        __syncthreads();

        if (kt < nkt - 1) {                    // prefetch next tile into regs
            gKh += (size_t)64 * D_; gKl += (size_t)64 * D_; gV += (size_t)64 * D_;
            rkh[0] = *(const shortx8*)(gKh);   rkh[1] = *(const shortx8*)(gKh + 8);
            rkl[0] = *(const shortx8*)(gKl);   rkl[1] = *(const shortx8*)(gKl + 8);
            rv[0]  = *(const shortx8*)(gV);    rv[1]  = *(const shortx8*)(gV + 8);
        }

        // ---- S^T = K @ Q^T (bf16x3, 32x32x16): sc[kf] = keys kf*32.. ----
        floatx16 sc[2] = {};
        __builtin_amdgcn_s_setprio(1);
        #pragma unroll
        for (int kf = 0; kf < 2; ++kf)
            #pragma unroll
            for (int c = 0; c < 4; ++c) {
                shortx8 ah = *(const shortx8*)&Ksh[kf * 32 + l31][c * 16 + hi * 8];
                shortx8 al = *(const shortx8*)&Ksl[kf * 32 + l31][c * 16 + hi * 8];
                sc[kf] = MFMA16(ah, qfh[c], sc[kf]);
                sc[kf] = MFMA16(al, qfh[c], sc[kf]);
                sc[kf] = MFMA16(ah, qfl[c], sc[kf]);
            }
        __builtin_amdgcn_s_setprio(0);

        // ---- causal mask (only tiles overlapping the diagonal zone) ----
        const int k0 = kt * 64;
        if (kt >= 2 * qt) {
            #pragma unroll
            for (int kf = 0; kf < 2; ++kf)
                #pragma unroll
                for (int r = 0; r < 16; ++r) {
                    int key = k0 + kf * 32 + (r & 3) + 8 * (r >> 2) + 4 * hi;
                    if (key > qg) sc[kf][r] = -1e30f;
                }
        }

        // ---- online softmax: row is lane-local + one xor(32) ----
        float t0 = -1e30f, t1 = -1e30f, t2 = -1e30f, t3 = -1e30f;
        #pragma unroll
        for (int kf = 0; kf < 2; ++kf)
            #pragma unroll
            for (int r = 0; r < 16; r += 4) {
                t0 = fmaxf(t0, sc[kf][r + 0]);
                t1 = fmaxf(t1, sc[kf][r + 1]);
                t2 = fmaxf(t2, sc[kf][r + 2]);
                t3 = fmaxf(t3, sc[kf][r + 3]);
            }
        float pm = fmaxf(fmaxf(t0, t1), fmaxf(t2, t3));
        pm = fmaxf(pm, __shfl_xor(pm, 32));
        const float mn   = fmaxf(mrow, pm);
        const float corr = __expf(mrow - mn);
        mrow = mn;
        float s0 = 0.f, s1 = 0.f, s2 = 0.f, s3 = 0.f;
        #pragma unroll
        for (int kf = 0; kf < 2; ++kf)
            #pragma unroll
            for (int r = 0; r < 16; r += 4) {
                s0 += (sc[kf][r + 0] = __expf(sc[kf][r + 0] - mn));
                s1 += (sc[kf][r + 1] = __expf(sc[kf][r + 1] - mn));
                s2 += (sc[kf][r + 2] = __expf(sc[kf][r + 2] - mn));
                s3 += (sc[kf][r + 3] = __expf(sc[kf][r + 3] - mn));
            }
        float ls = (s0 + s1) + (s2 + s3);
        ls += __shfl_xor(ls, 32);
        lsum = lsum * corr + ls;
        oacc[0] *= corr;
        oacc[1] *= corr;

        // ---- pack P -> bf16 B-frags (pure register, no LDS) ----
        // pb[kc2][j] = P^T[key = kc2*8 + hi*4 + j][q = l31]
        short4v pb[8];
        #pragma unroll
        for (int kc2 = 0; kc2 < 8; ++kc2)
            #pragma unroll
            for (int j = 0; j < 4; ++j)
                pb[kc2][j] = (short)f2bf(sc[kc2 >> 2][(kc2 & 3) * 4 + j]);

        // ---- O^T += V^T @ P^T (32x32x8) ----
        __builtin_amdgcn_s_setprio(1);
        #pragma unroll
        for (int kc2 = 0; kc2 < 8; ++kc2) {
            short4v va0 = *(const short4v*)&Vt[l31][kc2 * 8 + hi * 4];
            short4v va1 = *(const short4v*)&Vt[32 + l31][kc2 * 8 + hi * 4];
            oacc[0] = MFMA8(va0, pb[kc2], oacc[0]);
            oacc[1] = MFMA8(va1, pb[kc2], oacc[1]);
        }
        __builtin_amdgcn_s_setprio(0);
    }

    // ---- epilogue: O^T regs -> O[q][d] hi/lo planes (u32 d-pair stores) ----
    const float inv = 1.0f / lsum;
    #pragma unroll
    for (int df = 0; df < 2; ++df)
        #pragma unroll
        for (int rp = 0; rp < 8; ++rp) {
            const int r0 = rp * 2;
            const int d  = df * 32 + (r0 & 3) + 8 * (r0 >> 2) + 4 * hi;
            float v0 = oacc[df][r0] * inv;
            float v1 = oacc[df][r0 + 1] * inv;
            u16 h0 = f2bf(v0), h1 = f2bf(v1);
            u16 e0 = f2bf(v0 - bf2f(h0)), e1 = f2bf(v1 - bf2f(h1));
            size_t off = (rowbase + qg) * D_ + h * DK_ + d;
            *(u32*)(Oh + off) = (u32)h0 | ((u32)h1 << 16);
            *(u32*)(Ol + off) = (u32)e0 | ((u32)e1 << 16);
        }
}

// ---------------------------------------------------------------------------
// Launch
// ---------------------------------------------------------------------------
extern "C" void kernel_launch(void* const* d_in, const int* in_sizes, int n_in,
                              void* d_out, int out_size, void* d_ws, size_t ws_size,
                              hipStream_t stream)
{
    const float* x   = (const float*)d_in[0];
    const float* w_q = (const float*)d_in[1];
    const float* w_k = (const float*)d_in[2];
    const float* w_v = (const float*)d_in[3];
    const float* w_o = (const float*)d_in[4];
    float* out = (float*)d_out;

    const size_t TEN = (size_t)B_ * S_ * D_;   // 8388608
    const int    DD  = D_ * D_;                // 1048576
    const int    M   = B_ * S_;                // 8192

    u16* p    = (u16*)d_ws;
    u16* xh   = p;             u16* xl   = xh + TEN;
    u16* qh   = xl + TEN;      u16* ql   = qh + TEN;   // reused as attn out hi/lo
    u16* kh   = ql + TEN;      u16* kl   = kh + TEN;
    u16* vh   = kl + TEN;
    u16* wch  = vh + TEN;                              // concat QKV weights hi [3072][1024]
    u16* wcl  = wch + (size_t)3 * DD;                  // concat QKV weights lo
    u16* woh  = wcl + (size_t)3 * DD;
    u16* wol  = woh + DD;
    float2* rope = (float2*)(wol + DD);                // 65536 float2 = 512 KB

    // 1) split fp32 -> bf16 hi/lo planes; fill RoPE table
    split_bf16<<<(int)(TEN / 1024), 256, 0, stream>>>(x, xh, xl, (int)TEN);
    split_bf16<<<DD / 1024, 256, 0, stream>>>(w_q, wch,          wcl,          DD);
    split_bf16<<<DD / 1024, 256, 0, stream>>>(w_k, wch + DD,     wcl + DD,     DD);
    split_bf16<<<DD / 1024, 256, 0, stream>>>(w_v, wch + 2 * DD, wcl + 2 * DD, DD);
    split_bf16<<<DD / 1024, 256, 0, stream>>>(w_o, woh, wol, DD);
    fill_rope<<<256, 256, 0, stream>>>(rope);

    // 2) fused QKV projection (RoPE via table in epilogue; Q pre-scaled by 1/8)
    gemm_b3<3><<<dim3((M / 128) * (3 * D_ / 128)), 256, 0, stream>>>(
        xh, xl, wch, wcl, nullptr, qh, ql, kh, kl, vh, rope, M, 3 * D_, D_);

    // 3) flash attention v2 (output aliases q planes; block-disjoint regions)
    attn_mfma<<<dim3(S_ / 128, H_, B_), 256, 0, stream>>>(qh, ql, kh, kl, vh,
                                                          qh, ql);

    // 4) output projection -> fp32
    gemm_b3<0><<<dim3((M / 128) * (D_ / 128)), 256, 0, stream>>>(
        qh, ql, woh, wol, out, nullptr, nullptr, nullptr, nullptr, nullptr,
        nullptr, M, D_, D_);
}

// Round 9
// 532.537 us; speedup vs baseline: 2.0601x; 1.0219x over previous
//
#include <hip/hip_runtime.h>
#include <math.h>

// Problem constants (B=4, S=2048, D=1024, H=16, d_k=64)
#define B_  4
#define S_  2048
#define D_  1024
#define H_  16
#define DK_ 64

typedef unsigned short u16;
typedef unsigned int   u32;
typedef short     shortx8  __attribute__((ext_vector_type(8)));
typedef short     short4v  __attribute__((ext_vector_type(4)));
typedef float     floatx4  __attribute__((ext_vector_type(4)));
typedef float     floatx16 __attribute__((ext_vector_type(16)));
typedef u16       u16x4    __attribute__((ext_vector_type(4)));

// ---- bf16 helpers (RNE) ----
__device__ __forceinline__ u16 f2bf(float f) {
    u32 u = __float_as_uint(f);
    u += 0x7FFFu + ((u >> 16) & 1u);
    return (u16)(u >> 16);
}
__device__ __forceinline__ float bf2f(u16 b) {
    return __uint_as_float(((u32)b) << 16);
}

// ---- async global->LDS 16B (GEMM staging) ----
typedef const __attribute__((address_space(1))) u32* gp1_t;
typedef __attribute__((address_space(3))) u32* lp3_t;
__device__ __forceinline__ void async16(const void* g, void* l) {
    __builtin_amdgcn_global_load_lds((gp1_t)g, (lp3_t)l, 16, 0, 0);
}

#define MFMA32(a, b, c) __builtin_amdgcn_mfma_f32_16x16x32_bf16((a), (b), (c), 0, 0, 0)
#define MFMA16(a, b, c) __builtin_amdgcn_mfma_f32_32x32x16_bf16((a), (b), (c), 0, 0, 0)
// v_mfma_f32_32x32x8_bf16 (gfx950 ISA §10); clang builtin keeps the CDNA2 "_1k" name.
#define MFMA8(a, b, c)  __builtin_amdgcn_mfma_f32_32x32x8bf16_1k((a), (b), (c), 0, 0, 0)

// ---------------------------------------------------------------------------
// split fp32 -> (hi, lo) bf16 planes
// ---------------------------------------------------------------------------
__global__ __launch_bounds__(256)
void split_bf16(const float* __restrict__ src, u16* __restrict__ dh,
                u16* __restrict__ dl, int n)
{
    int i = (blockIdx.x * 256 + threadIdx.x) * 4;
    if (i >= n) return;
    float4 v = *(const float4*)(src + i);
    u16 h0 = f2bf(v.x), h1 = f2bf(v.y), h2 = f2bf(v.z), h3 = f2bf(v.w);
    u16x4 hv = {h0, h1, h2, h3};
    u16x4 lv = {f2bf(v.x - bf2f(h0)), f2bf(v.y - bf2f(h1)),
                f2bf(v.z - bf2f(h2)), f2bf(v.w - bf2f(h3))};
    *(u16x4*)(dh + i) = hv;
    *(u16x4*)(dl + i) = lv;
}

// ---------------------------------------------------------------------------
// RoPE cos/sin table: tab[s*32 + i] = (cos(s*f_i), sin(s*f_i)),
// f_i = 10000^(-i/32).  65536 entries = 512 KB, L2-hot thereafter.
// ---------------------------------------------------------------------------
__global__ __launch_bounds__(256)
void fill_rope(float2* __restrict__ tab)
{
    const int idx = blockIdx.x * 256 + threadIdx.x;   // 65536 total
    const int s = idx >> 5, i = idx & 31;
    const float fr = powf(10000.0f, -(float)i * (1.0f / 32.0f));
    float sa, ca;
    sincosf((float)s * fr, &sa, &ca);
    tab[idx] = make_float2(ca, sa);
}

// ---------------------------------------------------------------------------
// bf16x3 GEMM: C[M][N] = (Ah+Al)[M][K] @ (Wh+Wl)[N][K]^T  (3 MFMA passes)
// 128x128 tile, BK=32, 256 threads = 4 waves (2x2), 64x64 per wave.
// DOUBLE-BUFFERED LDS: one barrier per K-step; per step:
//   barrier (drains buf[cur] loads + prev reads) -> ds_read ALL frags of
//   buf[cur] (zero outstanding vmem => no spurious legalizer waits) ->
//   issue next tile's global_load_lds into buf[cur^1] -> MFMA (loads fly).
// LDS 64 KB -> 2 blocks/CU. 1-D grid, XCD-swizzled; mtiles hard-coded 64.
// EPI 0: fp32 out.  EPI 3: fused QKV epilogue (sel by n0>>10), RoPE via table.
// ---------------------------------------------------------------------------
template<int EPI>
__global__ __launch_bounds__(256, 1)
void gemm_b3(const u16* __restrict__ Ah, const u16* __restrict__ Al,
             const u16* __restrict__ Wh, const u16* __restrict__ Wl,
             float* __restrict__ outF,
             u16* __restrict__ qoh, u16* __restrict__ qol,
             u16* __restrict__ koh, u16* __restrict__ kol,
             u16* __restrict__ voh,
             const float2* __restrict__ rope,
             int M, int N, int K)
{
    __shared__ __align__(16) u16 As[2][2][128][32];   // [buf][plane][row][col]
    __shared__ __align__(16) u16 Ws[2][2][128][32];

    const int tid  = threadIdx.x;
    const int w    = tid >> 6;
    const int lane = tid & 63;
    const int lr   = lane & 15, lg = lane >> 4;
    const int wm   = w >> 1, wn = w & 1;

    // XCD-aware bijective swizzle (nwg multiple of 8); mtiles = 64
    const int cpx = gridDim.x >> 3;
    const int id  = blockIdx.x;
    const int swz = (id & 7) * cpx + (id >> 3);
    const int m0  = (swz & 63) * 128, n0 = (swz >> 6) * 128;

    const u16* gAh = Ah + (size_t)(m0 + w * 32 + (lane >> 2)) * K + (lane & 3) * 8;
    const u16* gAl = Al + (size_t)(m0 + w * 32 + (lane >> 2)) * K + (lane & 3) * 8;
    const u16* gWh = Wh + (size_t)(n0 + w * 32 + (lane >> 2)) * K + (lane & 3) * 8;
    const u16* gWl = Wl + (size_t)(n0 + w * 32 + (lane >> 2)) * K + (lane & 3) * 8;
    const size_t r16 = (size_t)16 * K;

    // wave-uniform LDS dests; lane's 16B lands at base + lane*16
    auto STAGE = [&](int buf, int kt) {
        async16(gAh + kt,       &As[buf][0][w * 32][0]);
        async16(gAh + kt + r16, &As[buf][0][w * 32 + 16][0]);
        async16(gAl + kt,       &As[buf][1][w * 32][0]);
        async16(gAl + kt + r16, &As[buf][1][w * 32 + 16][0]);
        async16(gWh + kt,       &Ws[buf][0][w * 32][0]);
        async16(gWh + kt + r16, &Ws[buf][0][w * 32 + 16][0]);
        async16(gWl + kt,       &Ws[buf][1][w * 32][0]);
        async16(gWl + kt + r16, &Ws[buf][1][w * 32 + 16][0]);
    };

    floatx4 zero = {0.f, 0.f, 0.f, 0.f};
    floatx4 acc[4][4];
    #pragma unroll
    for (int i = 0; i < 4; ++i)
        #pragma unroll
        for (int j = 0; j < 4; ++j) acc[i][j] = zero;

    STAGE(0, 0);
    int cur = 0;
    for (int kt = 0; kt < K; kt += 32) {
        __syncthreads();   // implicit vmcnt(0)+lgkmcnt(0): buf[cur] loads landed,
                           // all waves done reading buf[cur^1] (safe to restage)
        // read ALL fragments of buf[cur] first — no outstanding vmem here,
        // so the legalizer inserts no waits before these ds_reads
        shortx8 a0[4], a1[4], bw0[4], bw1[4];
        #pragma unroll
        for (int i = 0; i < 4; ++i) {
            a0[i]  = *(const shortx8*)&As[cur][0][wm * 64 + i * 16 + lr][lg * 8];
            a1[i]  = *(const shortx8*)&As[cur][1][wm * 64 + i * 16 + lr][lg * 8];
            bw0[i] = *(const shortx8*)&Ws[cur][0][wn * 64 + i * 16 + lr][lg * 8];
            bw1[i] = *(const shortx8*)&Ws[cur][1][wn * 64 + i * 16 + lr][lg * 8];
        }
        // prefetch next K-tile into the other buffer; flies during MFMA
        if (kt + 32 < K) STAGE(cur ^ 1, kt + 32);
        #pragma unroll
        for (int mi = 0; mi < 4; ++mi)
            #pragma unroll
            for (int ni = 0; ni < 4; ++ni) {
                acc[mi][ni] = MFMA32(a0[mi], bw0[ni], acc[mi][ni]);
                acc[mi][ni] = MFMA32(a0[mi], bw1[ni], acc[mi][ni]);
                acc[mi][ni] = MFMA32(a1[mi], bw0[ni], acc[mi][ni]);
            }
        cur ^= 1;
    }

    // C value (mi,ni,r): row = m0+wm*64+mi*16+lg*4+r, col = n0+wn*64+ni*16+lr
    if constexpr (EPI == 0) {
        #pragma unroll
        for (int mi = 0; mi < 4; ++mi)
            #pragma unroll
            for (int ni = 0; ni < 4; ++ni)
                #pragma unroll
                for (int r = 0; r < 4; ++r) {
                    size_t row = m0 + wm * 64 + mi * 16 + lg * 4 + r;
                    size_t col = n0 + wn * 64 + ni * 16 + lr;
                    outF[row * D_ + col] = acc[mi][ni][r];
                }
    }
    if constexpr (EPI == 3) {
        const int sel = n0 >> 10;
        const int ln0 = n0 & 1023;
        if (sel <= 1) {                         // Q or K: RoPE + hi/lo planes
            const float scale = (sel == 0) ? 0.125f : 1.0f;
            u16* oh = (sel == 0) ? qoh : koh;
            u16* ol = (sel == 0) ? qol : kol;
            #pragma unroll
            for (int ni = 0; ni < 4; ++ni) {
                const int pi = (ni * 16 + lr) >> 1;    // pair index 0..31
                #pragma unroll
                for (int mi = 0; mi < 4; ++mi)
                    #pragma unroll
                    for (int r = 0; r < 4; ++r) {
                        int row  = m0 + wm * 64 + mi * 16 + lg * 4 + r;
                        float2 cs = rope[((row & (S_ - 1)) << 5) + pi];
                        float v  = acc[mi][ni][r];
                        float pv = __shfl_xor(v, 1);
                        float o  = (v * cs.x + ((lr & 1) ? pv * cs.y : -pv * cs.y)) * scale;
                        u16 hv = f2bf(o);
                        u16 lv = f2bf(o - bf2f(hv));
                        u32 ph  = (u32)__shfl_xor((int)hv, 1) & 0xFFFFu;
                        u32 pl2 = (u32)__shfl_xor((int)lv, 1) & 0xFFFFu;
                        if (!(lr & 1)) {
                            size_t off = (size_t)row * D_ + ln0 + wn * 64 + ni * 16 + lr;
                            *(u32*)(oh + off) = (u32)hv | (ph << 16);
                            *(u32*)(ol + off) = (u32)lv | (pl2 << 16);
                        }
                    }
            }
        } else {                                // V: bf16-hi only
            #pragma unroll
            for (int mi = 0; mi < 4; ++mi)
                #pragma unroll
                for (int ni = 0; ni < 4; ++ni)
                    #pragma unroll
                    for (int r = 0; r < 4; ++r) {
                        float v = acc[mi][ni][r];
                        u16 hv = f2bf(v);
                        u32 ph = (u32)__shfl_xor((int)hv, 1) & 0xFFFFu;
                        if (!(lr & 1)) {
                            size_t row = m0 + wm * 64 + mi * 16 + lg * 4 + r;
                            size_t off = row * D_ + ln0 + wn * 64 + ni * 16 + lr;
                            *(u32*)(voh + off) = (u32)hv | (ph << 16);
                        }
                    }
        }
    }
}

// ---------------------------------------------------------------------------
// Flash attention v2 — swapped-operand MFMA, in-register softmax.
// (unchanged — passed R5/R6; left untouched for clean attribution)
// ---------------------------------------------------------------------------
__global__ __launch_bounds__(256)
void attn_mfma(const u16* __restrict__ Qh, const u16* __restrict__ Ql,
               const u16* __restrict__ Kh, const u16* __restrict__ Kl,
               const u16* __restrict__ Vh,
               u16* __restrict__ Oh, u16* __restrict__ Ol)
{
    __shared__ __align__(16) u16 Ksh[64][72];
    __shared__ __align__(16) u16 Ksl[64][72];
    __shared__ __align__(16) u16 Vt[64][68];

    const int tid  = threadIdx.x, w = tid >> 6, lane = tid & 63;
    const int l31  = lane & 31, hi = lane >> 5;
    const int qt   = gridDim.x - 1 - blockIdx.x;   // heavy tiles dispatch first
    const int h    = blockIdx.y, b = blockIdx.z;
    const int q0   = qt * 128;
    const size_t rowbase = (size_t)b * S_;
    const int qg   = q0 + w * 32 + l31;            // this lane's q row

    // Q fragments (B-operand, 32x32x16): chunk c covers k = c*16 + hi*8 + j
    shortx8 qfh[4], qfl[4];
    {
        const u16* qp  = Qh + (rowbase + qg) * D_ + h * DK_ + hi * 8;
        const u16* qp2 = Ql + (rowbase + qg) * D_ + h * DK_ + hi * 8;
        #pragma unroll
        for (int c = 0; c < 4; ++c) {
            qfh[c] = *(const shortx8*)(qp  + c * 16);
            qfl[c] = *(const shortx8*)(qp2 + c * 16);
        }
    }

    // staging addresses (tile 0)
    const int kr = tid >> 2, kc = (tid & 3) * 16;
    const u16* gKh = Kh + (rowbase + kr) * D_ + h * DK_ + kc;
    const u16* gKl = Kl + (rowbase + kr) * D_ + h * DK_ + kc;
    const u16* gV  = Vh + (rowbase + lane) * D_ + h * DK_ + w * 16;

    shortx8 rkh[2], rkl[2], rv[2];
    rkh[0] = *(const shortx8*)(gKh);   rkh[1] = *(const shortx8*)(gKh + 8);
    rkl[0] = *(const shortx8*)(gKl);   rkl[1] = *(const shortx8*)(gKl + 8);
    rv[0]  = *(const shortx8*)(gV);    rv[1]  = *(const shortx8*)(gV + 8);

    float mrow = -1e30f, lsum = 0.0f;
    floatx16 oacc[2] = {};

    const int nkt = 2 * qt + 2;
    for (int kt = 0; kt < nkt; ++kt) {
        __syncthreads();                       // prev tile's LDS reads done
        *(shortx8*)&Ksh[kr][kc]     = rkh[0];
        *(shortx8*)&Ksh[kr][kc + 8] = rkh[1];
        *(shortx8*)&Ksl[kr][kc]     = rkl[0];
        *(shortx8*)&Ksl[kr][kc + 8] = rkl[1];
        #pragma unroll
        for (int j = 0; j < 8; ++j) {          // V transpose: Vt[d][key]
            Vt[w * 16 + j][lane]     = (u16)rv[0][j];
            Vt[w * 16 + 8 + j][lane] = (u16)rv[1][j];
        }
        __syncthreads();

        if (kt < nkt - 1) {                    // prefetch next tile into regs
            gKh += (size_t)64 * D_; gKl += (size_t)64 * D_; gV += (size_t)64 * D_;
            rkh[0] = *(const shortx8*)(gKh);   rkh[1] = *(const shortx8*)(gKh + 8);
            rkl[0] = *(const shortx8*)(gKl);   rkl[1] = *(const shortx8*)(gKl + 8);
            rv[0]  = *(const shortx8*)(gV);    rv[1]  = *(const shortx8*)(gV + 8);
        }

        // ---- S^T = K @ Q^T (bf16x3, 32x32x16): sc[kf] = keys kf*32.. ----
        floatx16 sc[2] = {};
        __builtin_amdgcn_s_setprio(1);
        #pragma unroll
        for (int kf = 0; kf < 2; ++kf)
            #pragma unroll
            for (int c = 0; c < 4; ++c) {
                shortx8 ah = *(const shortx8*)&Ksh[kf * 32 + l31][c * 16 + hi * 8];
                shortx8 al = *(const shortx8*)&Ksl[kf * 32 + l31][c * 16 + hi * 8];
                sc[kf] = MFMA16(ah, qfh[c], sc[kf]);
                sc[kf] = MFMA16(al, qfh[c], sc[kf]);
                sc[kf] = MFMA16(ah, qfl[c], sc[kf]);
            }
        __builtin_amdgcn_s_setprio(0);

        // ---- causal mask (only tiles overlapping the diagonal zone) ----
        const int k0 = kt * 64;
        if (kt >= 2 * qt) {
            #pragma unroll
            for (int kf = 0; kf < 2; ++kf)
                #pragma unroll
                for (int r = 0; r < 16; ++r) {
                    int key = k0 + kf * 32 + (r & 3) + 8 * (r >> 2) + 4 * hi;
                    if (key > qg) sc[kf][r] = -1e30f;
                }
        }

        // ---- online softmax: row is lane-local + one xor(32) ----
        float t0 = -1e30f, t1 = -1e30f, t2 = -1e30f, t3 = -1e30f;
        #pragma unroll
        for (int kf = 0; kf < 2; ++kf)
            #pragma unroll
            for (int r = 0; r < 16; r += 4) {
                t0 = fmaxf(t0, sc[kf][r + 0]);
                t1 = fmaxf(t1, sc[kf][r + 1]);
                t2 = fmaxf(t2, sc[kf][r + 2]);
                t3 = fmaxf(t3, sc[kf][r + 3]);
            }
        float pm = fmaxf(fmaxf(t0, t1), fmaxf(t2, t3));
        pm = fmaxf(pm, __shfl_xor(pm, 32));
        const float mn   = fmaxf(mrow, pm);
        const float corr = __expf(mrow - mn);
        mrow = mn;
        float s0 = 0.f, s1 = 0.f, s2 = 0.f, s3 = 0.f;
        #pragma unroll
        for (int kf = 0; kf < 2; ++kf)
            #pragma unroll
            for (int r = 0; r < 16; r += 4) {
                s0 += (sc[kf][r + 0] = __expf(sc[kf][r + 0] - mn));
                s1 += (sc[kf][r + 1] = __expf(sc[kf][r + 1] - mn));
                s2 += (sc[kf][r + 2] = __expf(sc[kf][r + 2] - mn));
                s3 += (sc[kf][r + 3] = __expf(sc[kf][r + 3] - mn));
            }
        float ls = (s0 + s1) + (s2 + s3);
        ls += __shfl_xor(ls, 32);
        lsum = lsum * corr + ls;
        oacc[0] *= corr;
        oacc[1] *= corr;

        // ---- pack P -> bf16 B-frags (pure register, no LDS) ----
        // pb[kc2][j] = P^T[key = kc2*8 + hi*4 + j][q = l31]
        short4v pb[8];
        #pragma unroll
        for (int kc2 = 0; kc2 < 8; ++kc2)
            #pragma unroll
            for (int j = 0; j < 4; ++j)
                pb[kc2][j] = (short)f2bf(sc[kc2 >> 2][(kc2 & 3) * 4 + j]);

        // ---- O^T += V^T @ P^T (32x32x8) ----
        __builtin_amdgcn_s_setprio(1);
        #pragma unroll
        for (int kc2 = 0; kc2 < 8; ++kc2) {
            short4v va0 = *(const short4v*)&Vt[l31][kc2 * 8 + hi * 4];
            short4v va1 = *(const short4v*)&Vt[32 + l31][kc2 * 8 + hi * 4];
            oacc[0] = MFMA8(va0, pb[kc2], oacc[0]);
            oacc[1] = MFMA8(va1, pb[kc2], oacc[1]);
        }
        __builtin_amdgcn_s_setprio(0);
    }

    // ---- epilogue: O^T regs -> O[q][d] hi/lo planes (u32 d-pair stores) ----
    const float inv = 1.0f / lsum;
    #pragma unroll
    for (int df = 0; df < 2; ++df)
        #pragma unroll
        for (int rp = 0; rp < 8; ++rp) {
            const int r0 = rp * 2;
            const int d  = df * 32 + (r0 & 3) + 8 * (r0 >> 2) + 4 * hi;
            float v0 = oacc[df][r0] * inv;
            float v1 = oacc[df][r0 + 1] * inv;
            u16 h0 = f2bf(v0), h1 = f2bf(v1);
            u16 e0 = f2bf(v0 - bf2f(h0)), e1 = f2bf(v1 - bf2f(h1));
            size_t off = (rowbase + qg) * D_ + h * DK_ + d;
            *(u32*)(Oh + off) = (u32)h0 | ((u32)h1 << 16);
            *(u32*)(Ol + off) = (u32)e0 | ((u32)e1 << 16);
        }
}

// ---------------------------------------------------------------------------
// Launch
// ---------------------------------------------------------------------------
extern "C" void kernel_launch(void* const* d_in, const int* in_sizes, int n_in,
                              void* d_out, int out_size, void* d_ws, size_t ws_size,
                              hipStream_t stream)
{
    const float* x   = (const float*)d_in[0];
    const float* w_q = (const float*)d_in[1];
    const float* w_k = (const float*)d_in[2];
    const float* w_v = (const float*)d_in[3];
    const float* w_o = (const float*)d_in[4];
    float* out = (float*)d_out;

    const size_t TEN = (size_t)B_ * S_ * D_;   // 8388608
    const int    DD  = D_ * D_;                // 1048576
    const int    M   = B_ * S_;                // 8192

    u16* p    = (u16*)d_ws;
    u16* xh   = p;             u16* xl   = xh + TEN;
    u16* qh   = xl + TEN;      u16* ql   = qh + TEN;   // reused as attn out hi/lo
    u16* kh   = ql + TEN;      u16* kl   = kh + TEN;
    u16* vh   = kl + TEN;
    u16* wch  = vh + TEN;                              // concat QKV weights hi [3072][1024]
    u16* wcl  = wch + (size_t)3 * DD;                  // concat QKV weights lo
    u16* woh  = wcl + (size_t)3 * DD;
    u16* wol  = woh + DD;
    float2* rope = (float2*)(wol + DD);                // 65536 float2 = 512 KB

    // 1) split fp32 -> bf16 hi/lo planes; fill RoPE table
    split_bf16<<<(int)(TEN / 1024), 256, 0, stream>>>(x, xh, xl, (int)TEN);
    split_bf16<<<DD / 1024, 256, 0, stream>>>(w_q, wch,          wcl,          DD);
    split_bf16<<<DD / 1024, 256, 0, stream>>>(w_k, wch + DD,     wcl + DD,     DD);
    split_bf16<<<DD / 1024, 256, 0, stream>>>(w_v, wch + 2 * DD, wcl + 2 * DD, DD);
    split_bf16<<<DD / 1024, 256, 0, stream>>>(w_o, woh, wol, DD);
    fill_rope<<<256, 256, 0, stream>>>(rope);

    // 2) fused QKV projection (RoPE via table in epilogue; Q pre-scaled by 1/8)
    gemm_b3<3><<<dim3((M / 128) * (3 * D_ / 128)), 256, 0, stream>>>(
        xh, xl, wch, wcl, nullptr, qh, ql, kh, kl, vh, rope, M, 3 * D_, D_);

    // 3) flash attention v2 (output aliases q planes; block-disjoint regions)
    attn_mfma<<<dim3(S_ / 128, H_, B_), 256, 0, stream>>>(qh, ql, kh, kl, vh,
                                                          qh, ql);

    // 4) output projection -> fp32
    gemm_b3<0><<<dim3((M / 128) * (D_ / 128)), 256, 0, stream>>>(
        qh, ql, woh, wol, out, nullptr, nullptr, nullptr, nullptr, nullptr,
        nullptr, M, D_, D_);
}